// Round 22
// baseline (101.539 us; speedup 1.0000x reference)
//
#include <hip/hip_runtime.h>
#include <hip/hip_bf16.h>

typedef __attribute__((ext_vector_type(8))) short bf16x8;
typedef __attribute__((ext_vector_type(4))) float f32x4;

// Kinematic tree ancestor tables (full ancestor paths, from reference)
static constexpr int ALEN[24] = {0,1,1,1,2,2,2,3,3,3,4,4,4,4,4,5,5,5,6,6,7,7,8,8};
static constexpr int AOFF[24] = {0,0,1,2,3,5,7,9,12,15,18,22,26,30,34,38,43,48,53,59,65,72,79,87};
static constexpr int AFLAT[95] = {
  0, 0, 0,
  0,1, 0,2, 0,3,
  0,1,4, 0,2,5, 0,3,6,
  0,1,4,7, 0,2,5,8, 0,3,6,9, 0,3,6,9, 0,3,6,9,
  0,3,6,9,12, 0,3,6,9,13, 0,3,6,9,14,
  0,3,6,9,13,16, 0,3,6,9,14,17,
  0,3,6,9,13,16,18, 0,3,6,9,14,17,19,
  0,3,6,9,13,16,18,20, 0,3,6,9,14,17,19,21};
// Joints grouped by tree depth (ALEN value); independent within a level.
static constexpr int LVLN[9] = {1,3,3,3,5,3,2,2,2};
static constexpr int LVLJ[9][5] = {
  {0,0,0,0,0},{1,2,3,0,0},{4,5,6,0,0},{7,8,9,0,0},{10,11,12,13,14},
  {15,16,17,0,0},{18,19,0,0,0},{20,21,0,0,0},{22,23,0,0,0}};

static __device__ __forceinline__ unsigned short f2bf(float f) {
  unsigned int u = __float_as_uint(f);
  u = (u + 0x7fffu + ((u >> 16) & 1u)) >> 16;   // RTNE
  return (unsigned short)u;
}

static __device__ __forceinline__ bf16x8 pack8(float4 lo, float4 hi) {
  bf16x8 r;
  r[0] = (short)f2bf(lo.x); r[1] = (short)f2bf(lo.y);
  r[2] = (short)f2bf(lo.z); r[3] = (short)f2bf(lo.w);
  r[4] = (short)f2bf(hi.x); r[5] = (short)f2bf(hi.y);
  r[6] = (short)f2bf(hi.z); r[7] = (short)f2bf(hi.w);
  return r;
}

// ---------------------------------------------------------------------------
// K1: combine via MFMA  [r21 verbatim]
// ---------------------------------------------------------------------------
__global__ __launch_bounds__(640) void combine_mfma(const float* __restrict__ ktd,
                                                    const float* __restrict__ dcw,
                                                    const float* __restrict__ dsw,
                                                    const float* __restrict__ w2,
                                                    const float* __restrict__ b2,
                                                    const float* __restrict__ w1,
                                                    const float* __restrict__ b1,
                                                    float* __restrict__ Gp,
                                                    float* __restrict__ Hp,
                                                    float* __restrict__ S) {
  __shared__ float shpool[5760];                 // computeS: Sl[144][40]
  __shared__ float Wl[144][48];                  // computeS: substitution weights
  __shared__ unsigned short Bt[16][136];         // G/H: B tile, c-major (+8 pad)
  const int tid = threadIdx.x;
  const int bx = blockIdx.x, bz = blockIdx.y;

  if (bx >= 43) {                                // ---- computeS role ----
    if (bz != 0) return;
    for (int i = tid; i < 144 * 24; i += 640) {
      int t = i / 24, ch = i % 24;
      *(float2*)&Wl[t][ch * 2] = *(const float2*)(ktd + (size_t)t * 1078 + 1024 + ch * 2);
    }
    __syncthreads();
    float* Sl = shpool;                          // [144][40]
    const int c0 = (bx - 43) * 36;
    for (int lv = 0; lv < 9; lv++) {
      int units = LVLN[lv] * 54;
      for (int u = tid; u < units; u += 640) {
        int jj = u / 54, rem = u % 54, r = rem / 9, q = rem % 9;
        int j = LVLJ[lv][jj];
        int t = 6 * j + r;
        int cb = c0 + q * 4;
        f32x4 v;
        v[0] = (t == cb)     ? 1.f : 0.f;
        v[1] = (t == cb + 1) ? 1.f : 0.f;
        v[2] = (t == cb + 2) ? 1.f : 0.f;
        v[3] = (t == cb + 3) ? 1.f : 0.f;
        for (int a = 0; a < ALEN[j]; a++) {
          int anc = AFLAT[AOFF[j] + a];
          const float* w = &Wl[t][6 * a];
          #pragma unroll
          for (int k = 0; k < 6; k++) {
            f32x4 s4 = *(const f32x4*)&Sl[(anc * 6 + k) * 40 + q * 4];
            float wk = w[k];
            v[0] += wk * s4[0]; v[1] += wk * s4[1];
            v[2] += wk * s4[2]; v[3] += wk * s4[3];
          }
        }
        *(f32x4*)&Sl[t * 40 + q * 4] = v;
      }
      __syncthreads();
    }
    for (int i = tid; i < 144 * 36; i += 640) {
      int t = i / 36, cc = i % 36;
      S[t * 144 + c0 + cc] = Sl[t * 40 + cc];
    }
    return;
  }

  const int wv = tid >> 6, lane = tid & 63;
  const int m = lane & 15, g = lane >> 4;
  const int h0 = bz * 128;
  const bool isG = (bx < 26);
  const int c0 = isG ? bx * 16 : (bx - 26) * 16;
  const int NC = isG ? 400 : 266;                // weight col count (then bias col)
  const float* W = isG ? w2 : w1;
  const float* B = isG ? b2 : b1;

  // stage B tile: rows h0..h0+127, cols c0..c0+15 -> Bt[c][h] bf16 (coalesced)
  for (int i = tid; i < 2048; i += 640) {
    int h = i >> 4, c = i & 15, gc = c0 + c;
    float val = (gc < NC) ? W[(size_t)(h0 + h) * NC + gc]
              : ((gc == NC) ? B[h0 + h] : 0.f);
    Bt[c][h] = f2bf(val);
  }
  __syncthreads();

  if (isG) {                                     // ---- G role: 10 waves ----
    const int o = wv * 16 + m;                   // a-frag row
    const float* arow = (o < 144) ? (ktd + (size_t)o * 1078)
                      : ((o < 147) ? (dcw + (size_t)(o - 144) * 2051) : nullptr);
    f32x4 acc = (f32x4){0.f, 0.f, 0.f, 0.f};
    #pragma unroll
    for (int ks = 0; ks < 4; ks++) {
      const int hb = ks * 32 + g * 8;
      bf16x8 a;
      if (arow) {
        float4 lo = *(const float4*)(arow + h0 + hb);
        float4 hi = *(const float4*)(arow + h0 + hb + 4);
        a = pack8(lo, hi);
      } else {
        #pragma unroll
        for (int j = 0; j < 8; j++) a[j] = 0;
      }
      bf16x8 b = *(const bf16x8*)&Bt[m][hb];
      acc = __builtin_amdgcn_mfma_f32_16x16x32_bf16(a, b, acc, 0, 0, 0);
    }
    #pragma unroll
    for (int q = 0; q < 4; q++) {
      int oo = wv * 16 + g * 4 + q, cc = c0 + m;
      if (oo < 147 && cc < 401) Gp[(size_t)bz * 59200 + oo * 401 + cc] = acc[q];
    }
  } else {                                       // ---- H role: wave 0 ----
    if (wv != 0) return;
    const int o = m;
    const float* arow = (o < 10) ? (dsw + (size_t)o * 1024)
                      : ((o < 13) ? (dcw + (size_t)(o - 10) * 2051 + 1024) : nullptr);
    f32x4 acc = (f32x4){0.f, 0.f, 0.f, 0.f};
    #pragma unroll
    for (int ks = 0; ks < 4; ks++) {
      const int hb = ks * 32 + g * 8;
      bf16x8 a;
      if (arow) {
        float4 lo = *(const float4*)(arow + h0 + hb);
        float4 hi = *(const float4*)(arow + h0 + hb + 4);
        a = pack8(lo, hi);
      } else {
        #pragma unroll
        for (int j = 0; j < 8; j++) a[j] = 0;
      }
      bf16x8 b = *(const bf16x8*)&Bt[m][hb];
      acc = __builtin_amdgcn_mfma_f32_16x16x32_bf16(a, b, acc, 0, 0, 0);
    }
    #pragma unroll
    for (int q = 0; q < 4; q++) {
      int oo = g * 4 + q, cc = c0 + m;
      if (oo < 13 && cc < 267) Hp[(size_t)bz * 3520 + oo * 267 + cc] = acc[q];
    }
  }
}

static __device__ __forceinline__ float gsum(const float* __restrict__ Gp, int t, int c) {
  float s = 0.f;
  #pragma unroll
  for (int z = 0; z < 8; z++) s += Gp[(size_t)z * 59200 + t * 401 + c];
  return s;
}
static __device__ __forceinline__ float hsum(const float* __restrict__ Hp, int t, int c) {
  float s = 0.f;
  #pragma unroll
  for (int z = 0; z < 8; z++) s += Hp[(size_t)z * 3520 + t * 267 + c];
  return s;
}

// ---------------------------------------------------------------------------
// K2: assemble fp32 M0[160][424] + bias C0[160]  [r14 verbatim]
// ---------------------------------------------------------------------------
__global__ __launch_bounds__(256) void assembleM(const float* __restrict__ Gp,
                                                 const float* __restrict__ Hp,
                                                 const float* __restrict__ dcw,
                                                 const float* __restrict__ dcb,
                                                 const float* __restrict__ dsb,
                                                 const float* __restrict__ ktd,
                                                 const float* __restrict__ ktdb,
                                                 float* __restrict__ M0,
                                                 float* __restrict__ C0) {
  int o = blockIdx.x;
  for (int c = threadIdx.x; c < 424; c += 256) {
    float val = 0.f;
    if (c < 413) {
      if (o < 3) {
        if (c < 400) val += gsum(Gp, 144 + o, c);
        if (c < 256) val += hsum(Hp, 10 + o, c);
        if (c >= 400 && c < 410) val += hsum(Hp, 10 + o, 256 + (c - 400));
        if (c >= 410) {
          val += dcw[(size_t)o * 2051 + 2048 + (c - 410)];
          if ((c - 410) == o) val += 1.f;
        }
      } else if (o < 147) {
        int t = o - 3, j = t / 6;
        if (c < 400) val = gsum(Gp, t, c);
        int cj = c - 256 - j;            // init_pose[..., j:j+6] quirk slice
        if (cj >= 0 && cj < 6) val += ktd[(size_t)t * 1078 + 1024 + 6 * ALEN[j] + cj];
      } else if (o < 157) {
        int s = o - 147;
        if (c < 256) val = hsum(Hp, s, c);
        if (c >= 400 && c < 410) {
          val += hsum(Hp, s, 256 + (c - 400));
          if ((c - 400) == s) val += 1.f;
        }
      }
    }
    M0[o * 424 + c] = val;
  }
  if (threadIdx.x == 0 && o < 157) {
    float bv;
    if (o < 3)        bv = gsum(Gp, 144 + o, 400) + hsum(Hp, 10 + o, 266) + dcb[o];
    else if (o < 147) bv = gsum(Gp, o - 3, 400) + ktdb[o - 3];
    else              bv = hsum(Hp, o - 147, 266) + dsb[o - 147];
    C0[o] = bv;
  }
}

// ---------------------------------------------------------------------------
// K3: fold S into M  [r14 verbatim]
// ---------------------------------------------------------------------------
__global__ __launch_bounds__(256) void foldS(const float* __restrict__ S,
                                             const float* __restrict__ M0,
                                             const float* __restrict__ C0,
                                             unsigned short* __restrict__ Mb,
                                             float* __restrict__ Cb) {
  int o = blockIdx.x;
  int c = blockIdx.y * 212 + threadIdx.x;
  bool act = (threadIdx.x < 212) && (c < 424);
  if (o < 3 || o >= 147) {
    if (act) Mb[o * 424 + c] = f2bf(M0[o * 424 + c]);
    if (threadIdx.x == 0 && blockIdx.y == 0) Cb[o] = (o < 157) ? C0[o] : 0.f;
    return;
  }
  int t = o - 3;
  __shared__ float Sl[144];
  if (threadIdx.x < 144) Sl[threadIdx.x] = S[t * 144 + threadIdx.x];
  __syncthreads();
  if (act) {
    float acc = 0.f;
    #pragma unroll 16
    for (int k = 0; k < 144; k++) acc += Sl[k] * M0[(3 + k) * 424 + c];
    if (c == 256 + t) acc += 1.f;          // + init_pose fold
    Mb[o * 424 + c] = f2bf(acc);
  }
  if (threadIdx.x == 0 && blockIdx.y == 0) {
    float acc = 0.f;
    for (int k = 0; k < 144; k++) acc += Sl[k] * C0[3 + k];
    Cb[o] = acc;
  }
}

// ---------------------------------------------------------------------------
// K4: main GEMM  [r14 verbatim]
// ---------------------------------------------------------------------------
__global__ __launch_bounds__(512, 2) void main_gemm(const float* __restrict__ x,
                                                    const float* __restrict__ ipose,
                                                    const float* __restrict__ ishape,
                                                    const float* __restrict__ icam,
                                                    const unsigned short* __restrict__ Mb,
                                                    const float* __restrict__ Cb,
                                                    float* __restrict__ out) {
  __shared__ unsigned short Bl[160 * 424];       // 132.5 KB
  const int tid = threadIdx.x;

  {
    const bf16x8* src = (const bf16x8*)Mb;
    bf16x8* dst = (bf16x8*)Bl;
    for (int i = tid; i < 160 * 424 / 8; i += 512) dst[i] = src[i];
  }
  __syncthreads();

  const int w = tid >> 6, lane = tid & 63;
  const int m = lane & 15, g = lane >> 4;
  const int rowbase = blockIdx.x * 128 + w * 16;
  const int row = rowbase + m;
  const float* xr = x + (size_t)row * 256;
  const float* pr = ipose + (size_t)row * 144;

  float4 alo[13], ahi[13];
  #pragma unroll
  for (int k = 0; k < 8; k++) {
    const float* p = xr + k * 32 + g * 8;
    alo[k] = *(const float4*)p; ahi[k] = *(const float4*)(p + 4);
  }
  #pragma unroll
  for (int k = 8; k < 12; k++) {
    const float* p = pr + (k - 8) * 32 + g * 8;
    alo[k] = *(const float4*)p; ahi[k] = *(const float4*)(p + 4);
  }
  if (g < 2) {
    const float* p = pr + 128 + g * 8;
    alo[12] = *(const float4*)p; ahi[12] = *(const float4*)(p + 4);
  } else if (g == 2) {
    const float* p = ishape + (size_t)row * 10;
    alo[12] = make_float4(p[0], p[1], p[2], p[3]);
    ahi[12] = make_float4(p[4], p[5], p[6], p[7]);
  } else {
    const float* p = ishape + (size_t)row * 10;
    const float* q = icam + (size_t)row * 3;
    alo[12] = make_float4(p[8], p[9], q[0], q[1]);
    ahi[12] = make_float4(q[2], 0.f, 0.f, 0.f);
  }
  bf16x8 areg[13];
  #pragma unroll
  for (int k = 0; k < 13; k++) areg[k] = pack8(alo[k], ahi[k]);

  f32x4 acc[10];
  #pragma unroll
  for (int n = 0; n < 10; n++) acc[n] = (f32x4){0.f, 0.f, 0.f, 0.f};

  #pragma unroll
  for (int k = 0; k < 13; k++) {
    #pragma unroll
    for (int n = 0; n < 10; n++) {
      bf16x8 b = *(const bf16x8*)&Bl[(n * 16 + m) * 424 + k * 32 + g * 8];
      acc[n] = __builtin_amdgcn_mfma_f32_16x16x32_bf16(areg[k], b, acc[n], 0, 0, 0);
    }
  }

  // epilogue: C/D layout col=lane&15, row=(lane>>4)*4+reg  [m89-verified]
  #pragma unroll
  for (int n = 0; n < 10; n++) {
    int col = n * 16 + m;
    if (col < 157) {
      float bias = Cb[col];
      #pragma unroll
      for (int q = 0; q < 4; q++)
        out[(size_t)(rowbase + g * 4 + q) * 157 + col] = acc[n][q] + bias;
    }
  }
}

// ---------------------------------------------------------------------------
extern "C" void kernel_launch(void* const* d_in, const int* in_sizes, int n_in,
                              void* d_out, int out_size, void* d_ws, size_t ws_size,
                              hipStream_t stream) {
  const float* x      = (const float*)d_in[0];
  const float* ipose  = (const float*)d_in[1];
  const float* ishape = (const float*)d_in[2];
  const float* icam   = (const float*)d_in[3];
  const float* fc1w   = (const float*)d_in[4];
  const float* fc1b   = (const float*)d_in[5];
  const float* fc2w   = (const float*)d_in[6];
  const float* fc2b   = (const float*)d_in[7];
  const float* dsw    = (const float*)d_in[8];
  const float* dsb    = (const float*)d_in[9];
  const float* dcw    = (const float*)d_in[10];
  const float* dcb    = (const float*)d_in[11];
  const float* ktd    = (const float*)d_in[12];
  const float* ktdb   = (const float*)d_in[13];
  int rows = in_sizes[0] / 256;
  float* ws = (float*)d_ws;

  float* Gp = ws;                                      // 8*59200 = 473600 f
  float* Hp = ws + 473600;                             // 8*3520  = 28160 f -> 501760
  float* M0 = ws + 501760;                             // 160*424 = 67840 f -> 569600
  float* C0 = ws + 569600;                             // 160 f -> 569760
  float* S  = ws + 569760;                             // 144*144 = 20736 f -> 590496
  float* Cb = ws + 590496;                             // 160 f -> 590656
  unsigned short* Mb = (unsigned short*)(ws + 590656); // byte 2362624 (16-aligned)

  // MEASUREMENT ROUND (r12 technique): setup chain launched 3x (idempotent);
  // (T22 - T21)/2 = setup_exec + 3 gaps. main_gemm once.
  for (int rep = 0; rep < 3; rep++) {
    combine_mfma<<<dim3(47, 8), 640, 0, stream>>>(ktd, dcw, dsw, fc2w, fc2b,
                                                  fc1w, fc1b, Gp, Hp, S);
    assembleM<<<160, 256, 0, stream>>>(Gp, Hp, dcw, dcb, dsb, ktd, ktdb, M0, C0);
    foldS<<<dim3(160, 2), 256, 0, stream>>>(S, M0, C0, Mb, Cb);
  }
  main_gemm<<<rows / 128, 512, 0, stream>>>(x, ipose, ishape, icam, Mb, Cb,
                                            (float*)d_out);
}

// Round 23
// 67.508 us; speedup vs baseline: 1.5041x; 1.5041x over previous
//
#include <hip/hip_runtime.h>
#include <hip/hip_bf16.h>

typedef __attribute__((ext_vector_type(8))) short bf16x8;
typedef __attribute__((ext_vector_type(4))) float f32x4;

// Kinematic tree ancestor tables (full ancestor paths, from reference)
static constexpr int ALEN[24] = {0,1,1,1,2,2,2,3,3,3,4,4,4,4,4,5,5,5,6,6,7,7,8,8};
static constexpr int AOFF[24] = {0,0,1,2,3,5,7,9,12,15,18,22,26,30,34,38,43,48,53,59,65,72,79,87};
static constexpr int AFLAT[95] = {
  0, 0, 0,
  0,1, 0,2, 0,3,
  0,1,4, 0,2,5, 0,3,6,
  0,1,4,7, 0,2,5,8, 0,3,6,9, 0,3,6,9, 0,3,6,9,
  0,3,6,9,12, 0,3,6,9,13, 0,3,6,9,14,
  0,3,6,9,13,16, 0,3,6,9,14,17,
  0,3,6,9,13,16,18, 0,3,6,9,14,17,19,
  0,3,6,9,13,16,18,20, 0,3,6,9,14,17,19,21};
// Joints grouped by tree depth (ALEN value); independent within a level.
static constexpr int LVLN[9] = {1,3,3,3,5,3,2,2,2};
static constexpr int LVLJ[9][5] = {
  {0,0,0,0,0},{1,2,3,0,0},{4,5,6,0,0},{7,8,9,0,0},{10,11,12,13,14},
  {15,16,17,0,0},{18,19,0,0,0},{20,21,0,0,0},{22,23,0,0,0}};

static __device__ __forceinline__ unsigned short f2bf(float f) {
  unsigned int u = __float_as_uint(f);
  u = (u + 0x7fffu + ((u >> 16) & 1u)) >> 16;   // RTNE
  return (unsigned short)u;
}

static __device__ __forceinline__ bf16x8 pack8(float4 lo, float4 hi) {
  bf16x8 r;
  r[0] = (short)f2bf(lo.x); r[1] = (short)f2bf(lo.y);
  r[2] = (short)f2bf(lo.z); r[3] = (short)f2bf(lo.w);
  r[4] = (short)f2bf(hi.x); r[5] = (short)f2bf(hi.y);
  r[6] = (short)f2bf(hi.z); r[7] = (short)f2bf(hi.w);
  return r;
}

// ---------------------------------------------------------------------------
// K1: combine via MFMA — repacked to 229 blocks (ONE block-wave on 256 CUs).
//   bx <  208 : G tile (bz = bx/26, c-tile = bx%26)   [r21 math verbatim]
//   bx <  225 : H tile (c-tile = bx-208), loops all 8 bz internally
//   bx >= 225 : computeS (4 blocks)                    [r21 verbatim]
// ---------------------------------------------------------------------------
__global__ __launch_bounds__(640) void combine_mfma(const float* __restrict__ ktd,
                                                    const float* __restrict__ dcw,
                                                    const float* __restrict__ dsw,
                                                    const float* __restrict__ w2,
                                                    const float* __restrict__ b2,
                                                    const float* __restrict__ w1,
                                                    const float* __restrict__ b1,
                                                    float* __restrict__ Gp,
                                                    float* __restrict__ Hp,
                                                    float* __restrict__ S) {
  __shared__ float shpool[5760];                 // computeS: Sl[144][40]
  __shared__ float Wl[144][48];                  // computeS: substitution weights
  __shared__ unsigned short Bt[16][136];         // G/H: B tile, c-major (+8 pad)
  const int tid = threadIdx.x;
  const int bx = blockIdx.x;

  if (bx >= 225) {                               // ---- computeS role ----
    for (int i = tid; i < 144 * 24; i += 640) {
      int t = i / 24, ch = i % 24;
      *(float2*)&Wl[t][ch * 2] = *(const float2*)(ktd + (size_t)t * 1078 + 1024 + ch * 2);
    }
    __syncthreads();
    float* Sl = shpool;                          // [144][40]
    const int c0 = (bx - 225) * 36;
    for (int lv = 0; lv < 9; lv++) {
      int units = LVLN[lv] * 54;
      for (int u = tid; u < units; u += 640) {
        int jj = u / 54, rem = u % 54, r = rem / 9, q = rem % 9;
        int j = LVLJ[lv][jj];
        int t = 6 * j + r;
        int cb = c0 + q * 4;
        f32x4 v;
        v[0] = (t == cb)     ? 1.f : 0.f;
        v[1] = (t == cb + 1) ? 1.f : 0.f;
        v[2] = (t == cb + 2) ? 1.f : 0.f;
        v[3] = (t == cb + 3) ? 1.f : 0.f;
        for (int a = 0; a < ALEN[j]; a++) {
          int anc = AFLAT[AOFF[j] + a];
          const float* w = &Wl[t][6 * a];
          #pragma unroll
          for (int k = 0; k < 6; k++) {
            f32x4 s4 = *(const f32x4*)&Sl[(anc * 6 + k) * 40 + q * 4];
            float wk = w[k];
            v[0] += wk * s4[0]; v[1] += wk * s4[1];
            v[2] += wk * s4[2]; v[3] += wk * s4[3];
          }
        }
        *(f32x4*)&Sl[t * 40 + q * 4] = v;
      }
      __syncthreads();
    }
    for (int i = tid; i < 144 * 36; i += 640) {
      int t = i / 36, cc = i % 36;
      S[t * 144 + c0 + cc] = Sl[t * 40 + cc];
    }
    return;
  }

  const int wv = tid >> 6, lane = tid & 63;
  const int m = lane & 15, g = lane >> 4;

  if (bx < 208) {                                // ---- G role ----
    const int bz = bx / 26;
    const int c0 = (bx % 26) * 16;
    const int h0 = bz * 128;
    // stage B tile (coalesced)
    for (int i = tid; i < 2048; i += 640) {
      int h = i >> 4, c = i & 15, gc = c0 + c;
      float val = (gc < 400) ? w2[(size_t)(h0 + h) * 400 + gc]
                : ((gc == 400) ? b2[h0 + h] : 0.f);
      Bt[c][h] = f2bf(val);
    }
    __syncthreads();
    const int o = wv * 16 + m;                   // a-frag row
    const float* arow = (o < 144) ? (ktd + (size_t)o * 1078)
                      : ((o < 147) ? (dcw + (size_t)(o - 144) * 2051) : nullptr);
    f32x4 acc = (f32x4){0.f, 0.f, 0.f, 0.f};
    #pragma unroll
    for (int ks = 0; ks < 4; ks++) {
      const int hb = ks * 32 + g * 8;
      bf16x8 a;
      if (arow) {
        float4 lo = *(const float4*)(arow + h0 + hb);
        float4 hi = *(const float4*)(arow + h0 + hb + 4);
        a = pack8(lo, hi);
      } else {
        #pragma unroll
        for (int j = 0; j < 8; j++) a[j] = 0;
      }
      bf16x8 b = *(const bf16x8*)&Bt[m][hb];
      acc = __builtin_amdgcn_mfma_f32_16x16x32_bf16(a, b, acc, 0, 0, 0);
    }
    #pragma unroll
    for (int q = 0; q < 4; q++) {
      int oo = wv * 16 + g * 4 + q, cc = c0 + m;
      if (oo < 147 && cc < 401) Gp[(size_t)bz * 59200 + oo * 401 + cc] = acc[q];
    }
  } else {                                       // ---- H role: loops 8 bz ----
    const int c0 = (bx - 208) * 16;
    const int o = m;
    const float* arow = (o < 10) ? (dsw + (size_t)o * 1024)
                      : ((o < 13) ? (dcw + (size_t)(o - 10) * 2051 + 1024) : nullptr);
    for (int bz = 0; bz < 8; bz++) {
      const int h0 = bz * 128;
      __syncthreads();                           // Bt reuse guard
      for (int i = tid; i < 2048; i += 640) {
        int h = i >> 4, c = i & 15, gc = c0 + c;
        float val = (gc < 266) ? w1[(size_t)(h0 + h) * 266 + gc]
                  : ((gc == 266) ? b1[h0 + h] : 0.f);
        Bt[c][h] = f2bf(val);
      }
      __syncthreads();
      if (wv == 0) {
        f32x4 acc = (f32x4){0.f, 0.f, 0.f, 0.f};
        #pragma unroll
        for (int ks = 0; ks < 4; ks++) {
          const int hb = ks * 32 + g * 8;
          bf16x8 a;
          if (arow) {
            float4 lo = *(const float4*)(arow + h0 + hb);
            float4 hi = *(const float4*)(arow + h0 + hb + 4);
            a = pack8(lo, hi);
          } else {
            #pragma unroll
            for (int j = 0; j < 8; j++) a[j] = 0;
          }
          bf16x8 b = *(const bf16x8*)&Bt[m][hb];
          acc = __builtin_amdgcn_mfma_f32_16x16x32_bf16(a, b, acc, 0, 0, 0);
        }
        #pragma unroll
        for (int q = 0; q < 4; q++) {
          int oo = g * 4 + q, cc = c0 + m;
          if (oo < 13 && cc < 267) Hp[(size_t)bz * 3520 + oo * 267 + cc] = acc[q];
        }
      }
    }
  }
}

static __device__ __forceinline__ float gsum(const float* __restrict__ Gp, int t, int c) {
  float s = 0.f;
  #pragma unroll
  for (int z = 0; z < 8; z++) s += Gp[(size_t)z * 59200 + t * 401 + c];
  return s;
}
static __device__ __forceinline__ float hsum(const float* __restrict__ Hp, int t, int c) {
  float s = 0.f;
  #pragma unroll
  for (int z = 0; z < 8; z++) s += Hp[(size_t)z * 3520 + t * 267 + c];
  return s;
}

// ---------------------------------------------------------------------------
// K2: assemble fp32 M0[160][424] + bias C0[160]  [r14 verbatim]
// ---------------------------------------------------------------------------
__global__ __launch_bounds__(256) void assembleM(const float* __restrict__ Gp,
                                                 const float* __restrict__ Hp,
                                                 const float* __restrict__ dcw,
                                                 const float* __restrict__ dcb,
                                                 const float* __restrict__ dsb,
                                                 const float* __restrict__ ktd,
                                                 const float* __restrict__ ktdb,
                                                 float* __restrict__ M0,
                                                 float* __restrict__ C0) {
  int o = blockIdx.x;
  for (int c = threadIdx.x; c < 424; c += 256) {
    float val = 0.f;
    if (c < 413) {
      if (o < 3) {
        if (c < 400) val += gsum(Gp, 144 + o, c);
        if (c < 256) val += hsum(Hp, 10 + o, c);
        if (c >= 400 && c < 410) val += hsum(Hp, 10 + o, 256 + (c - 400));
        if (c >= 410) {
          val += dcw[(size_t)o * 2051 + 2048 + (c - 410)];
          if ((c - 410) == o) val += 1.f;
        }
      } else if (o < 147) {
        int t = o - 3, j = t / 6;
        if (c < 400) val = gsum(Gp, t, c);
        int cj = c - 256 - j;            // init_pose[..., j:j+6] quirk slice
        if (cj >= 0 && cj < 6) val += ktd[(size_t)t * 1078 + 1024 + 6 * ALEN[j] + cj];
      } else if (o < 157) {
        int s = o - 147;
        if (c < 256) val = hsum(Hp, s, c);
        if (c >= 400 && c < 410) {
          val += hsum(Hp, s, 256 + (c - 400));
          if ((c - 400) == s) val += 1.f;
        }
      }
    }
    M0[o * 424 + c] = val;
  }
  if (threadIdx.x == 0 && o < 157) {
    float bv;
    if (o < 3)        bv = gsum(Gp, 144 + o, 400) + hsum(Hp, 10 + o, 266) + dcb[o];
    else if (o < 147) bv = gsum(Gp, o - 3, 400) + ktdb[o - 3];
    else              bv = hsum(Hp, o - 147, 266) + dsb[o - 147];
    C0[o] = bv;
  }
}

// ---------------------------------------------------------------------------
// K3: fold S into M — repacked to 160 blocks (one block-wave); each thread
// strides both c-halves. Per-element math identical to r14's foldS.
// ---------------------------------------------------------------------------
__global__ __launch_bounds__(256) void foldS(const float* __restrict__ S,
                                             const float* __restrict__ M0,
                                             const float* __restrict__ C0,
                                             unsigned short* __restrict__ Mb,
                                             float* __restrict__ Cb) {
  int o = blockIdx.x;
  if (o < 3 || o >= 147) {
    for (int c = threadIdx.x; c < 424; c += 256)
      Mb[o * 424 + c] = f2bf(M0[o * 424 + c]);
    if (threadIdx.x == 0) Cb[o] = (o < 157) ? C0[o] : 0.f;
    return;
  }
  int t = o - 3;
  __shared__ float Sl[144];
  if (threadIdx.x < 144) Sl[threadIdx.x] = S[t * 144 + threadIdx.x];
  __syncthreads();
  for (int c = threadIdx.x; c < 424; c += 256) {
    float acc = 0.f;
    #pragma unroll 16
    for (int k = 0; k < 144; k++) acc += Sl[k] * M0[(3 + k) * 424 + c];
    if (c == 256 + t) acc += 1.f;          // + init_pose fold
    Mb[o * 424 + c] = f2bf(acc);
  }
  if (threadIdx.x == 0) {
    float acc = 0.f;
    for (int k = 0; k < 144; k++) acc += Sl[k] * C0[3 + k];
    Cb[o] = acc;
  }
}

// ---------------------------------------------------------------------------
// K4: main GEMM  [r14 verbatim]
// ---------------------------------------------------------------------------
__global__ __launch_bounds__(512, 2) void main_gemm(const float* __restrict__ x,
                                                    const float* __restrict__ ipose,
                                                    const float* __restrict__ ishape,
                                                    const float* __restrict__ icam,
                                                    const unsigned short* __restrict__ Mb,
                                                    const float* __restrict__ Cb,
                                                    float* __restrict__ out) {
  __shared__ unsigned short Bl[160 * 424];       // 132.5 KB
  const int tid = threadIdx.x;

  {
    const bf16x8* src = (const bf16x8*)Mb;
    bf16x8* dst = (bf16x8*)Bl;
    for (int i = tid; i < 160 * 424 / 8; i += 512) dst[i] = src[i];
  }
  __syncthreads();

  const int w = tid >> 6, lane = tid & 63;
  const int m = lane & 15, g = lane >> 4;
  const int rowbase = blockIdx.x * 128 + w * 16;
  const int row = rowbase + m;
  const float* xr = x + (size_t)row * 256;
  const float* pr = ipose + (size_t)row * 144;

  float4 alo[13], ahi[13];
  #pragma unroll
  for (int k = 0; k < 8; k++) {
    const float* p = xr + k * 32 + g * 8;
    alo[k] = *(const float4*)p; ahi[k] = *(const float4*)(p + 4);
  }
  #pragma unroll
  for (int k = 8; k < 12; k++) {
    const float* p = pr + (k - 8) * 32 + g * 8;
    alo[k] = *(const float4*)p; ahi[k] = *(const float4*)(p + 4);
  }
  if (g < 2) {
    const float* p = pr + 128 + g * 8;
    alo[12] = *(const float4*)p; ahi[12] = *(const float4*)(p + 4);
  } else if (g == 2) {
    const float* p = ishape + (size_t)row * 10;
    alo[12] = make_float4(p[0], p[1], p[2], p[3]);
    ahi[12] = make_float4(p[4], p[5], p[6], p[7]);
  } else {
    const float* p = ishape + (size_t)row * 10;
    const float* q = icam + (size_t)row * 3;
    alo[12] = make_float4(p[8], p[9], q[0], q[1]);
    ahi[12] = make_float4(q[2], 0.f, 0.f, 0.f);
  }
  bf16x8 areg[13];
  #pragma unroll
  for (int k = 0; k < 13; k++) areg[k] = pack8(alo[k], ahi[k]);

  f32x4 acc[10];
  #pragma unroll
  for (int n = 0; n < 10; n++) acc[n] = (f32x4){0.f, 0.f, 0.f, 0.f};

  #pragma unroll
  for (int k = 0; k < 13; k++) {
    #pragma unroll
    for (int n = 0; n < 10; n++) {
      bf16x8 b = *(const bf16x8*)&Bl[(n * 16 + m) * 424 + k * 32 + g * 8];
      acc[n] = __builtin_amdgcn_mfma_f32_16x16x32_bf16(areg[k], b, acc[n], 0, 0, 0);
    }
  }

  // epilogue: C/D layout col=lane&15, row=(lane>>4)*4+reg  [m89-verified]
  #pragma unroll
  for (int n = 0; n < 10; n++) {
    int col = n * 16 + m;
    if (col < 157) {
      float bias = Cb[col];
      #pragma unroll
      for (int q = 0; q < 4; q++)
        out[(size_t)(rowbase + g * 4 + q) * 157 + col] = acc[n][q] + bias;
    }
  }
}

// ---------------------------------------------------------------------------
extern "C" void kernel_launch(void* const* d_in, const int* in_sizes, int n_in,
                              void* d_out, int out_size, void* d_ws, size_t ws_size,
                              hipStream_t stream) {
  const float* x      = (const float*)d_in[0];
  const float* ipose  = (const float*)d_in[1];
  const float* ishape = (const float*)d_in[2];
  const float* icam   = (const float*)d_in[3];
  const float* fc1w   = (const float*)d_in[4];
  const float* fc1b   = (const float*)d_in[5];
  const float* fc2w   = (const float*)d_in[6];
  const float* fc2b   = (const float*)d_in[7];
  const float* dsw    = (const float*)d_in[8];
  const float* dsb    = (const float*)d_in[9];
  const float* dcw    = (const float*)d_in[10];
  const float* dcb    = (const float*)d_in[11];
  const float* ktd    = (const float*)d_in[12];
  const float* ktdb   = (const float*)d_in[13];
  int rows = in_sizes[0] / 256;
  float* ws = (float*)d_ws;

  float* Gp = ws;                                      // 8*59200 = 473600 f
  float* Hp = ws + 473600;                             // 8*3520  = 28160 f -> 501760
  float* M0 = ws + 501760;                             // 160*424 = 67840 f -> 569600
  float* C0 = ws + 569600;                             // 160 f -> 569760
  float* S  = ws + 569760;                             // 144*144 = 20736 f -> 590496
  float* Cb = ws + 590496;                             // 160 f -> 590656
  unsigned short* Mb = (unsigned short*)(ws + 590656); // byte 2362624 (16-aligned)

  combine_mfma<<<229, 640, 0, stream>>>(ktd, dcw, dsw, fc2w, fc2b,
                                        fc1w, fc1b, Gp, Hp, S);
  assembleM<<<160, 256, 0, stream>>>(Gp, Hp, dcw, dcb, dsb, ktd, ktdb, M0, C0);
  foldS<<<160, 256, 0, stream>>>(S, M0, C0, Mb, Cb);
  main_gemm<<<rows / 128, 512, 0, stream>>>(x, ipose, ishape, icam, Mb, Cb,
                                            (float*)d_out);
}

// Round 24
// 55.394 us; speedup vs baseline: 1.8330x; 1.2187x over previous
//
#include <hip/hip_runtime.h>
#include <hip/hip_bf16.h>

typedef __attribute__((ext_vector_type(8))) short bf16x8;
typedef __attribute__((ext_vector_type(4))) float f32x4;

// Kinematic tree ancestor tables (full ancestor paths, from reference)
static constexpr int ALEN[24] = {0,1,1,1,2,2,2,3,3,3,4,4,4,4,4,5,5,5,6,6,7,7,8,8};
static constexpr int AOFF[24] = {0,0,1,2,3,5,7,9,12,15,18,22,26,30,34,38,43,48,53,59,65,72,79,87};
static constexpr int AFLAT[95] = {
  0, 0, 0,
  0,1, 0,2, 0,3,
  0,1,4, 0,2,5, 0,3,6,
  0,1,4,7, 0,2,5,8, 0,3,6,9, 0,3,6,9, 0,3,6,9,
  0,3,6,9,12, 0,3,6,9,13, 0,3,6,9,14,
  0,3,6,9,13,16, 0,3,6,9,14,17,
  0,3,6,9,13,16,18, 0,3,6,9,14,17,19,
  0,3,6,9,13,16,18,20, 0,3,6,9,14,17,19,21};
// Joints grouped by tree depth (ALEN value); independent within a level.
static constexpr int LVLN[9] = {1,3,3,3,5,3,2,2,2};
static constexpr int LVLJ[9][5] = {
  {0,0,0,0,0},{1,2,3,0,0},{4,5,6,0,0},{7,8,9,0,0},{10,11,12,13,14},
  {15,16,17,0,0},{18,19,0,0,0},{20,21,0,0,0},{22,23,0,0,0}};

static __device__ __forceinline__ unsigned short f2bf(float f) {
  unsigned int u = __float_as_uint(f);
  u = (u + 0x7fffu + ((u >> 16) & 1u)) >> 16;   // RTNE
  return (unsigned short)u;
}

static __device__ __forceinline__ bf16x8 pack8(float4 lo, float4 hi) {
  bf16x8 r;
  r[0] = (short)f2bf(lo.x); r[1] = (short)f2bf(lo.y);
  r[2] = (short)f2bf(lo.z); r[3] = (short)f2bf(lo.w);
  r[4] = (short)f2bf(hi.x); r[5] = (short)f2bf(hi.y);
  r[6] = (short)f2bf(hi.z); r[7] = (short)f2bf(hi.w);
  return r;
}

// ---------------------------------------------------------------------------
// K1: combine via MFMA  [r21 verbatim — 51.4 µs best config]
// ---------------------------------------------------------------------------
__global__ __launch_bounds__(640) void combine_mfma(const float* __restrict__ ktd,
                                                    const float* __restrict__ dcw,
                                                    const float* __restrict__ dsw,
                                                    const float* __restrict__ w2,
                                                    const float* __restrict__ b2,
                                                    const float* __restrict__ w1,
                                                    const float* __restrict__ b1,
                                                    float* __restrict__ Gp,
                                                    float* __restrict__ Hp,
                                                    float* __restrict__ S) {
  __shared__ float shpool[5760];                 // computeS: Sl[144][40]
  __shared__ float Wl[144][48];                  // computeS: substitution weights
  __shared__ unsigned short Bt[16][136];         // G/H: B tile, c-major (+8 pad)
  const int tid = threadIdx.x;
  const int bx = blockIdx.x, bz = blockIdx.y;

  if (bx >= 43) {                                // ---- computeS role ----
    if (bz != 0) return;
    for (int i = tid; i < 144 * 24; i += 640) {
      int t = i / 24, ch = i % 24;
      *(float2*)&Wl[t][ch * 2] = *(const float2*)(ktd + (size_t)t * 1078 + 1024 + ch * 2);
    }
    __syncthreads();
    float* Sl = shpool;                          // [144][40]
    const int c0 = (bx - 43) * 36;
    for (int lv = 0; lv < 9; lv++) {
      int units = LVLN[lv] * 54;
      for (int u = tid; u < units; u += 640) {
        int jj = u / 54, rem = u % 54, r = rem / 9, q = rem % 9;
        int j = LVLJ[lv][jj];
        int t = 6 * j + r;
        int cb = c0 + q * 4;
        f32x4 v;
        v[0] = (t == cb)     ? 1.f : 0.f;
        v[1] = (t == cb + 1) ? 1.f : 0.f;
        v[2] = (t == cb + 2) ? 1.f : 0.f;
        v[3] = (t == cb + 3) ? 1.f : 0.f;
        for (int a = 0; a < ALEN[j]; a++) {
          int anc = AFLAT[AOFF[j] + a];
          const float* w = &Wl[t][6 * a];
          #pragma unroll
          for (int k = 0; k < 6; k++) {
            f32x4 s4 = *(const f32x4*)&Sl[(anc * 6 + k) * 40 + q * 4];
            float wk = w[k];
            v[0] += wk * s4[0]; v[1] += wk * s4[1];
            v[2] += wk * s4[2]; v[3] += wk * s4[3];
          }
        }
        *(f32x4*)&Sl[t * 40 + q * 4] = v;
      }
      __syncthreads();
    }
    for (int i = tid; i < 144 * 36; i += 640) {
      int t = i / 36, cc = i % 36;
      S[t * 144 + c0 + cc] = Sl[t * 40 + cc];
    }
    return;
  }

  const int wv = tid >> 6, lane = tid & 63;
  const int m = lane & 15, g = lane >> 4;
  const int h0 = bz * 128;
  const bool isG = (bx < 26);
  const int c0 = isG ? bx * 16 : (bx - 26) * 16;
  const int NC = isG ? 400 : 266;                // weight col count (then bias col)
  const float* W = isG ? w2 : w1;
  const float* B = isG ? b2 : b1;

  // stage B tile: rows h0..h0+127, cols c0..c0+15 -> Bt[c][h] bf16 (coalesced)
  for (int i = tid; i < 2048; i += 640) {
    int h = i >> 4, c = i & 15, gc = c0 + c;
    float val = (gc < NC) ? W[(size_t)(h0 + h) * NC + gc]
              : ((gc == NC) ? B[h0 + h] : 0.f);
    Bt[c][h] = f2bf(val);
  }
  __syncthreads();

  if (isG) {                                     // ---- G role: 10 waves ----
    const int o = wv * 16 + m;                   // a-frag row
    const float* arow = (o < 144) ? (ktd + (size_t)o * 1078)
                      : ((o < 147) ? (dcw + (size_t)(o - 144) * 2051) : nullptr);
    f32x4 acc = (f32x4){0.f, 0.f, 0.f, 0.f};
    #pragma unroll
    for (int ks = 0; ks < 4; ks++) {
      const int hb = ks * 32 + g * 8;
      bf16x8 a;
      if (arow) {
        float4 lo = *(const float4*)(arow + h0 + hb);
        float4 hi = *(const float4*)(arow + h0 + hb + 4);
        a = pack8(lo, hi);
      } else {
        #pragma unroll
        for (int j = 0; j < 8; j++) a[j] = 0;
      }
      bf16x8 b = *(const bf16x8*)&Bt[m][hb];
      acc = __builtin_amdgcn_mfma_f32_16x16x32_bf16(a, b, acc, 0, 0, 0);
    }
    #pragma unroll
    for (int q = 0; q < 4; q++) {
      int oo = wv * 16 + g * 4 + q, cc = c0 + m;
      if (oo < 147 && cc < 401) Gp[(size_t)bz * 59200 + oo * 401 + cc] = acc[q];
    }
  } else {                                       // ---- H role: wave 0 ----
    if (wv != 0) return;
    const int o = m;
    const float* arow = (o < 10) ? (dsw + (size_t)o * 1024)
                      : ((o < 13) ? (dcw + (size_t)(o - 10) * 2051 + 1024) : nullptr);
    f32x4 acc = (f32x4){0.f, 0.f, 0.f, 0.f};
    #pragma unroll
    for (int ks = 0; ks < 4; ks++) {
      const int hb = ks * 32 + g * 8;
      bf16x8 a;
      if (arow) {
        float4 lo = *(const float4*)(arow + h0 + hb);
        float4 hi = *(const float4*)(arow + h0 + hb + 4);
        a = pack8(lo, hi);
      } else {
        #pragma unroll
        for (int j = 0; j < 8; j++) a[j] = 0;
      }
      bf16x8 b = *(const bf16x8*)&Bt[m][hb];
      acc = __builtin_amdgcn_mfma_f32_16x16x32_bf16(a, b, acc, 0, 0, 0);
    }
    #pragma unroll
    for (int q = 0; q < 4; q++) {
      int oo = g * 4 + q, cc = c0 + m;
      if (oo < 13 && cc < 267) Hp[(size_t)bz * 3520 + oo * 267 + cc] = acc[q];
    }
  }
}

static __device__ __forceinline__ float gsum(const float* __restrict__ Gp, int t, int c) {
  float s = 0.f;
  #pragma unroll
  for (int z = 0; z < 8; z++) s += Gp[(size_t)z * 59200 + t * 401 + c];
  return s;
}
static __device__ __forceinline__ float hsum(const float* __restrict__ Hp, int t, int c) {
  float s = 0.f;
  #pragma unroll
  for (int z = 0; z < 8; z++) s += Hp[(size_t)z * 3520 + t * 267 + c];
  return s;
}

// ---------------------------------------------------------------------------
// K2: assemble fp32 M0[160][424] + bias C0[160]  [r14 verbatim]
// ---------------------------------------------------------------------------
__global__ __launch_bounds__(256) void assembleM(const float* __restrict__ Gp,
                                                 const float* __restrict__ Hp,
                                                 const float* __restrict__ dcw,
                                                 const float* __restrict__ dcb,
                                                 const float* __restrict__ dsb,
                                                 const float* __restrict__ ktd,
                                                 const float* __restrict__ ktdb,
                                                 float* __restrict__ M0,
                                                 float* __restrict__ C0) {
  int o = blockIdx.x;
  for (int c = threadIdx.x; c < 424; c += 256) {
    float val = 0.f;
    if (c < 413) {
      if (o < 3) {
        if (c < 400) val += gsum(Gp, 144 + o, c);
        if (c < 256) val += hsum(Hp, 10 + o, c);
        if (c >= 400 && c < 410) val += hsum(Hp, 10 + o, 256 + (c - 400));
        if (c >= 410) {
          val += dcw[(size_t)o * 2051 + 2048 + (c - 410)];
          if ((c - 410) == o) val += 1.f;
        }
      } else if (o < 147) {
        int t = o - 3, j = t / 6;
        if (c < 400) val = gsum(Gp, t, c);
        int cj = c - 256 - j;            // init_pose[..., j:j+6] quirk slice
        if (cj >= 0 && cj < 6) val += ktd[(size_t)t * 1078 + 1024 + 6 * ALEN[j] + cj];
      } else if (o < 157) {
        int s = o - 147;
        if (c < 256) val = hsum(Hp, s, c);
        if (c >= 400 && c < 410) {
          val += hsum(Hp, s, 256 + (c - 400));
          if ((c - 400) == s) val += 1.f;
        }
      }
    }
    M0[o * 424 + c] = val;
  }
  if (threadIdx.x == 0 && o < 157) {
    float bv;
    if (o < 3)        bv = gsum(Gp, 144 + o, 400) + hsum(Hp, 10 + o, 266) + dcb[o];
    else if (o < 147) bv = gsum(Gp, o - 3, 400) + ktdb[o - 3];
    else              bv = hsum(Hp, o - 147, 266) + dsb[o - 147];
    C0[o] = bv;
  }
}

// ---------------------------------------------------------------------------
// K3: fold S into M  [r14 verbatim]
// ---------------------------------------------------------------------------
__global__ __launch_bounds__(256) void foldS(const float* __restrict__ S,
                                             const float* __restrict__ M0,
                                             const float* __restrict__ C0,
                                             unsigned short* __restrict__ Mb,
                                             float* __restrict__ Cb) {
  int o = blockIdx.x;
  int c = blockIdx.y * 212 + threadIdx.x;
  bool act = (threadIdx.x < 212) && (c < 424);
  if (o < 3 || o >= 147) {
    if (act) Mb[o * 424 + c] = f2bf(M0[o * 424 + c]);
    if (threadIdx.x == 0 && blockIdx.y == 0) Cb[o] = (o < 157) ? C0[o] : 0.f;
    return;
  }
  int t = o - 3;
  __shared__ float Sl[144];
  if (threadIdx.x < 144) Sl[threadIdx.x] = S[t * 144 + threadIdx.x];
  __syncthreads();
  if (act) {
    float acc = 0.f;
    #pragma unroll 16
    for (int k = 0; k < 144; k++) acc += Sl[k] * M0[(3 + k) * 424 + c];
    if (c == 256 + t) acc += 1.f;          // + init_pose fold
    Mb[o * 424 + c] = f2bf(acc);
  }
  if (threadIdx.x == 0 && blockIdx.y == 0) {
    float acc = 0.f;
    for (int k = 0; k < 144; k++) acc += Sl[k] * C0[3 + k];
    Cb[o] = acc;
  }
}

// ---------------------------------------------------------------------------
// K4: main GEMM — r14 structure, but A-LOADS ISSUED BEFORE the Mb staging so
// their HBM latency hides under the staging's L2 traffic. Pins on the packed
// areg words (52 VGPRs) keep pressure under the (512,2) 128-VGPR cap.
// ---------------------------------------------------------------------------
__global__ __launch_bounds__(512, 2) void main_gemm(const float* __restrict__ x,
                                                    const float* __restrict__ ipose,
                                                    const float* __restrict__ ishape,
                                                    const float* __restrict__ icam,
                                                    const unsigned short* __restrict__ Mb,
                                                    const float* __restrict__ Cb,
                                                    float* __restrict__ out) {
  __shared__ unsigned short Bl[160 * 424];       // 132.5 KB
  const int tid = threadIdx.x;
  const int w = tid >> 6, lane = tid & 63;
  const int m = lane & 15, g = lane >> 4;
  const int rowbase = blockIdx.x * 128 + w * 16;
  const int row = rowbase + m;
  const float* xr = x + (size_t)row * 256;
  const float* pr = ipose + (size_t)row * 144;

  // ---- A loads + pack FIRST (latency overlapped with staging below) ----
  bf16x8 areg[13];
  #pragma unroll
  for (int k = 0; k < 8; k++) {
    const float* p = xr + k * 32 + g * 8;
    areg[k] = pack8(*(const float4*)p, *(const float4*)(p + 4));
  }
  #pragma unroll
  for (int k = 8; k < 12; k++) {
    const float* p = pr + (k - 8) * 32 + g * 8;
    areg[k] = pack8(*(const float4*)p, *(const float4*)(p + 4));
  }
  if (g < 2) {
    const float* p = pr + 128 + g * 8;
    areg[12] = pack8(*(const float4*)p, *(const float4*)(p + 4));
  } else if (g == 2) {
    const float* p = ishape + (size_t)row * 10;
    areg[12] = pack8(make_float4(p[0], p[1], p[2], p[3]),
                     make_float4(p[4], p[5], p[6], p[7]));
  } else {
    const float* p = ishape + (size_t)row * 10;
    const float* q = icam + (size_t)row * 3;
    areg[12] = pack8(make_float4(p[8], p[9], q[0], q[1]),
                     make_float4(q[2], 0.f, 0.f, 0.f));
  }
  // pin packed fragments (scalar 32-bit words) -> loads must issue here
  #pragma unroll
  for (int k = 0; k < 13; k++) {
    int4 t = *(const int4*)&areg[k];
    asm volatile("" :: "v"(t.x), "v"(t.y), "v"(t.z), "v"(t.w));
  }

  // ---- stage Mb -> LDS (L2-resident; covers the A-load latency) ----
  {
    const bf16x8* src = (const bf16x8*)Mb;
    bf16x8* dst = (bf16x8*)Bl;
    for (int i = tid; i < 160 * 424 / 8; i += 512) dst[i] = src[i];
  }
  __syncthreads();

  f32x4 acc[10];
  #pragma unroll
  for (int n = 0; n < 10; n++) acc[n] = (f32x4){0.f, 0.f, 0.f, 0.f};

  #pragma unroll
  for (int k = 0; k < 13; k++) {
    #pragma unroll
    for (int n = 0; n < 10; n++) {
      bf16x8 b = *(const bf16x8*)&Bl[(n * 16 + m) * 424 + k * 32 + g * 8];
      acc[n] = __builtin_amdgcn_mfma_f32_16x16x32_bf16(areg[k], b, acc[n], 0, 0, 0);
    }
  }

  // epilogue: C/D layout col=lane&15, row=(lane>>4)*4+reg  [m89-verified]
  #pragma unroll
  for (int n = 0; n < 10; n++) {
    int col = n * 16 + m;
    if (col < 157) {
      float bias = Cb[col];
      #pragma unroll
      for (int q = 0; q < 4; q++)
        out[(size_t)(rowbase + g * 4 + q) * 157 + col] = acc[n][q] + bias;
    }
  }
}

// ---------------------------------------------------------------------------
extern "C" void kernel_launch(void* const* d_in, const int* in_sizes, int n_in,
                              void* d_out, int out_size, void* d_ws, size_t ws_size,
                              hipStream_t stream) {
  const float* x      = (const float*)d_in[0];
  const float* ipose  = (const float*)d_in[1];
  const float* ishape = (const float*)d_in[2];
  const float* icam   = (const float*)d_in[3];
  const float* fc1w   = (const float*)d_in[4];
  const float* fc1b   = (const float*)d_in[5];
  const float* fc2w   = (const float*)d_in[6];
  const float* fc2b   = (const float*)d_in[7];
  const float* dsw    = (const float*)d_in[8];
  const float* dsb    = (const float*)d_in[9];
  const float* dcw    = (const float*)d_in[10];
  const float* dcb    = (const float*)d_in[11];
  const float* ktd    = (const float*)d_in[12];
  const float* ktdb   = (const float*)d_in[13];
  int rows = in_sizes[0] / 256;
  float* ws = (float*)d_ws;

  float* Gp = ws;                                      // 8*59200 = 473600 f
  float* Hp = ws + 473600;                             // 8*3520  = 28160 f -> 501760
  float* M0 = ws + 501760;                             // 160*424 = 67840 f -> 569600
  float* C0 = ws + 569600;                             // 160 f -> 569760
  float* S  = ws + 569760;                             // 144*144 = 20736 f -> 590496
  float* Cb = ws + 590496;                             // 160 f -> 590656
  unsigned short* Mb = (unsigned short*)(ws + 590656); // byte 2362624 (16-aligned)

  combine_mfma<<<dim3(47, 8), 640, 0, stream>>>(ktd, dcw, dsw, fc2w, fc2b,
                                                fc1w, fc1b, Gp, Hp, S);
  assembleM<<<160, 256, 0, stream>>>(Gp, Hp, dcw, dcb, dsb, ktd, ktdb, M0, C0);
  foldS<<<dim3(160, 2), 256, 0, stream>>>(S, M0, C0, Mb, Cb);
  main_gemm<<<rows / 128, 512, 0, stream>>>(x, ipose, ishape, icam, Mb, Cb,
                                            (float*)d_out);
}

// Round 25
// 51.173 us; speedup vs baseline: 1.9842x; 1.0825x over previous
//
#include <hip/hip_runtime.h>
#include <hip/hip_bf16.h>

typedef __attribute__((ext_vector_type(8))) short bf16x8;
typedef __attribute__((ext_vector_type(4))) float f32x4;

// Kinematic tree ancestor tables (full ancestor paths, from reference)
static constexpr int ALEN[24] = {0,1,1,1,2,2,2,3,3,3,4,4,4,4,4,5,5,5,6,6,7,7,8,8};
static constexpr int AOFF[24] = {0,0,1,2,3,5,7,9,12,15,18,22,26,30,34,38,43,48,53,59,65,72,79,87};
static constexpr int AFLAT[95] = {
  0, 0, 0,
  0,1, 0,2, 0,3,
  0,1,4, 0,2,5, 0,3,6,
  0,1,4,7, 0,2,5,8, 0,3,6,9, 0,3,6,9, 0,3,6,9,
  0,3,6,9,12, 0,3,6,9,13, 0,3,6,9,14,
  0,3,6,9,13,16, 0,3,6,9,14,17,
  0,3,6,9,13,16,18, 0,3,6,9,14,17,19,
  0,3,6,9,13,16,18,20, 0,3,6,9,14,17,19,21};
// Joints grouped by tree depth (ALEN value); independent within a level.
static constexpr int LVLN[9] = {1,3,3,3,5,3,2,2,2};
static constexpr int LVLJ[9][5] = {
  {0,0,0,0,0},{1,2,3,0,0},{4,5,6,0,0},{7,8,9,0,0},{10,11,12,13,14},
  {15,16,17,0,0},{18,19,0,0,0},{20,21,0,0,0},{22,23,0,0,0}};

static __device__ __forceinline__ unsigned short f2bf(float f) {
  unsigned int u = __float_as_uint(f);
  u = (u + 0x7fffu + ((u >> 16) & 1u)) >> 16;   // RTNE
  return (unsigned short)u;
}

static __device__ __forceinline__ bf16x8 pack8(float4 lo, float4 hi) {
  bf16x8 r;
  r[0] = (short)f2bf(lo.x); r[1] = (short)f2bf(lo.y);
  r[2] = (short)f2bf(lo.z); r[3] = (short)f2bf(lo.w);
  r[4] = (short)f2bf(hi.x); r[5] = (short)f2bf(hi.y);
  r[6] = (short)f2bf(hi.z); r[7] = (short)f2bf(hi.w);
  return r;
}

// ---------------------------------------------------------------------------
// K1: combine via MFMA  [r21 verbatim — best config]
// ---------------------------------------------------------------------------
__global__ __launch_bounds__(640) void combine_mfma(const float* __restrict__ ktd,
                                                    const float* __restrict__ dcw,
                                                    const float* __restrict__ dsw,
                                                    const float* __restrict__ w2,
                                                    const float* __restrict__ b2,
                                                    const float* __restrict__ w1,
                                                    const float* __restrict__ b1,
                                                    float* __restrict__ Gp,
                                                    float* __restrict__ Hp,
                                                    float* __restrict__ S) {
  __shared__ float shpool[5760];                 // computeS: Sl[144][40]
  __shared__ float Wl[144][48];                  // computeS: substitution weights
  __shared__ unsigned short Bt[16][136];         // G/H: B tile, c-major (+8 pad)
  const int tid = threadIdx.x;
  const int bx = blockIdx.x, bz = blockIdx.y;

  if (bx >= 43) {                                // ---- computeS role ----
    if (bz != 0) return;
    for (int i = tid; i < 144 * 24; i += 640) {
      int t = i / 24, ch = i % 24;
      *(float2*)&Wl[t][ch * 2] = *(const float2*)(ktd + (size_t)t * 1078 + 1024 + ch * 2);
    }
    __syncthreads();
    float* Sl = shpool;                          // [144][40]
    const int c0 = (bx - 43) * 36;
    for (int lv = 0; lv < 9; lv++) {
      int units = LVLN[lv] * 54;
      for (int u = tid; u < units; u += 640) {
        int jj = u / 54, rem = u % 54, r = rem / 9, q = rem % 9;
        int j = LVLJ[lv][jj];
        int t = 6 * j + r;
        int cb = c0 + q * 4;
        f32x4 v;
        v[0] = (t == cb)     ? 1.f : 0.f;
        v[1] = (t == cb + 1) ? 1.f : 0.f;
        v[2] = (t == cb + 2) ? 1.f : 0.f;
        v[3] = (t == cb + 3) ? 1.f : 0.f;
        for (int a = 0; a < ALEN[j]; a++) {
          int anc = AFLAT[AOFF[j] + a];
          const float* w = &Wl[t][6 * a];
          #pragma unroll
          for (int k = 0; k < 6; k++) {
            f32x4 s4 = *(const f32x4*)&Sl[(anc * 6 + k) * 40 + q * 4];
            float wk = w[k];
            v[0] += wk * s4[0]; v[1] += wk * s4[1];
            v[2] += wk * s4[2]; v[3] += wk * s4[3];
          }
        }
        *(f32x4*)&Sl[t * 40 + q * 4] = v;
      }
      __syncthreads();
    }
    for (int i = tid; i < 144 * 36; i += 640) {
      int t = i / 36, cc = i % 36;
      S[t * 144 + c0 + cc] = Sl[t * 40 + cc];
    }
    return;
  }

  const int wv = tid >> 6, lane = tid & 63;
  const int m = lane & 15, g = lane >> 4;
  const int h0 = bz * 128;
  const bool isG = (bx < 26);
  const int c0 = isG ? bx * 16 : (bx - 26) * 16;
  const int NC = isG ? 400 : 266;                // weight col count (then bias col)
  const float* W = isG ? w2 : w1;
  const float* B = isG ? b2 : b1;

  // stage B tile: rows h0..h0+127, cols c0..c0+15 -> Bt[c][h] bf16 (coalesced)
  for (int i = tid; i < 2048; i += 640) {
    int h = i >> 4, c = i & 15, gc = c0 + c;
    float val = (gc < NC) ? W[(size_t)(h0 + h) * NC + gc]
              : ((gc == NC) ? B[h0 + h] : 0.f);
    Bt[c][h] = f2bf(val);
  }
  __syncthreads();

  if (isG) {                                     // ---- G role: 10 waves ----
    const int o = wv * 16 + m;                   // a-frag row
    const float* arow = (o < 144) ? (ktd + (size_t)o * 1078)
                      : ((o < 147) ? (dcw + (size_t)(o - 144) * 2051) : nullptr);
    f32x4 acc = (f32x4){0.f, 0.f, 0.f, 0.f};
    #pragma unroll
    for (int ks = 0; ks < 4; ks++) {
      const int hb = ks * 32 + g * 8;
      bf16x8 a;
      if (arow) {
        float4 lo = *(const float4*)(arow + h0 + hb);
        float4 hi = *(const float4*)(arow + h0 + hb + 4);
        a = pack8(lo, hi);
      } else {
        #pragma unroll
        for (int j = 0; j < 8; j++) a[j] = 0;
      }
      bf16x8 b = *(const bf16x8*)&Bt[m][hb];
      acc = __builtin_amdgcn_mfma_f32_16x16x32_bf16(a, b, acc, 0, 0, 0);
    }
    #pragma unroll
    for (int q = 0; q < 4; q++) {
      int oo = wv * 16 + g * 4 + q, cc = c0 + m;
      if (oo < 147 && cc < 401) Gp[(size_t)bz * 59200 + oo * 401 + cc] = acc[q];
    }
  } else {                                       // ---- H role: wave 0 ----
    if (wv != 0) return;
    const int o = m;
    const float* arow = (o < 10) ? (dsw + (size_t)o * 1024)
                      : ((o < 13) ? (dcw + (size_t)(o - 10) * 2051 + 1024) : nullptr);
    f32x4 acc = (f32x4){0.f, 0.f, 0.f, 0.f};
    #pragma unroll
    for (int ks = 0; ks < 4; ks++) {
      const int hb = ks * 32 + g * 8;
      bf16x8 a;
      if (arow) {
        float4 lo = *(const float4*)(arow + h0 + hb);
        float4 hi = *(const float4*)(arow + h0 + hb + 4);
        a = pack8(lo, hi);
      } else {
        #pragma unroll
        for (int j = 0; j < 8; j++) a[j] = 0;
      }
      bf16x8 b = *(const bf16x8*)&Bt[m][hb];
      acc = __builtin_amdgcn_mfma_f32_16x16x32_bf16(a, b, acc, 0, 0, 0);
    }
    #pragma unroll
    for (int q = 0; q < 4; q++) {
      int oo = g * 4 + q, cc = c0 + m;
      if (oo < 13 && cc < 267) Hp[(size_t)bz * 3520 + oo * 267 + cc] = acc[q];
    }
  }
}

static __device__ __forceinline__ float gsum(const float* __restrict__ Gp, int t, int c) {
  float s = 0.f;
  #pragma unroll
  for (int z = 0; z < 8; z++) s += Gp[(size_t)z * 59200 + t * 401 + c];
  return s;
}
static __device__ __forceinline__ float hsum(const float* __restrict__ Hp, int t, int c) {
  float s = 0.f;
  #pragma unroll
  for (int z = 0; z < 8; z++) s += Hp[(size_t)z * 3520 + t * 267 + c];
  return s;
}

// ---------------------------------------------------------------------------
// K2: assemble fp32 M0[160][424] + bias C0[160]  [r14 verbatim]
// ---------------------------------------------------------------------------
__global__ __launch_bounds__(256) void assembleM(const float* __restrict__ Gp,
                                                 const float* __restrict__ Hp,
                                                 const float* __restrict__ dcw,
                                                 const float* __restrict__ dcb,
                                                 const float* __restrict__ dsb,
                                                 const float* __restrict__ ktd,
                                                 const float* __restrict__ ktdb,
                                                 float* __restrict__ M0,
                                                 float* __restrict__ C0) {
  int o = blockIdx.x;
  for (int c = threadIdx.x; c < 424; c += 256) {
    float val = 0.f;
    if (c < 413) {
      if (o < 3) {
        if (c < 400) val += gsum(Gp, 144 + o, c);
        if (c < 256) val += hsum(Hp, 10 + o, c);
        if (c >= 400 && c < 410) val += hsum(Hp, 10 + o, 256 + (c - 400));
        if (c >= 410) {
          val += dcw[(size_t)o * 2051 + 2048 + (c - 410)];
          if ((c - 410) == o) val += 1.f;
        }
      } else if (o < 147) {
        int t = o - 3, j = t / 6;
        if (c < 400) val = gsum(Gp, t, c);
        int cj = c - 256 - j;            // init_pose[..., j:j+6] quirk slice
        if (cj >= 0 && cj < 6) val += ktd[(size_t)t * 1078 + 1024 + 6 * ALEN[j] + cj];
      } else if (o < 157) {
        int s = o - 147;
        if (c < 256) val = hsum(Hp, s, c);
        if (c >= 400 && c < 410) {
          val += hsum(Hp, s, 256 + (c - 400));
          if ((c - 400) == s) val += 1.f;
        }
      }
    }
    M0[o * 424 + c] = val;
  }
  if (threadIdx.x == 0 && o < 157) {
    float bv;
    if (o < 3)        bv = gsum(Gp, 144 + o, 400) + hsum(Hp, 10 + o, 266) + dcb[o];
    else if (o < 147) bv = gsum(Gp, o - 3, 400) + ktdb[o - 3];
    else              bv = hsum(Hp, o - 147, 266) + dsb[o - 147];
    C0[o] = bv;
  }
}

// ---------------------------------------------------------------------------
// K3: fold S into M  [r14 verbatim]
// ---------------------------------------------------------------------------
__global__ __launch_bounds__(256) void foldS(const float* __restrict__ S,
                                             const float* __restrict__ M0,
                                             const float* __restrict__ C0,
                                             unsigned short* __restrict__ Mb,
                                             float* __restrict__ Cb) {
  int o = blockIdx.x;
  int c = blockIdx.y * 212 + threadIdx.x;
  bool act = (threadIdx.x < 212) && (c < 424);
  if (o < 3 || o >= 147) {
    if (act) Mb[o * 424 + c] = f2bf(M0[o * 424 + c]);
    if (threadIdx.x == 0 && blockIdx.y == 0) Cb[o] = (o < 157) ? C0[o] : 0.f;
    return;
  }
  int t = o - 3;
  __shared__ float Sl[144];
  if (threadIdx.x < 144) Sl[threadIdx.x] = S[t * 144 + threadIdx.x];
  __syncthreads();
  if (act) {
    float acc = 0.f;
    #pragma unroll 16
    for (int k = 0; k < 144; k++) acc += Sl[k] * M0[(3 + k) * 424 + c];
    if (c == 256 + t) acc += 1.f;          // + init_pose fold
    Mb[o * 424 + c] = f2bf(acc);
  }
  if (threadIdx.x == 0 && blockIdx.y == 0) {
    float acc = 0.f;
    for (int k = 0; k < 144; k++) acc += Sl[k] * C0[3 + k];
    Cb[o] = acc;
  }
}

// ---------------------------------------------------------------------------
// K4: main GEMM  [r14 verbatim]
// ---------------------------------------------------------------------------
__global__ __launch_bounds__(512, 2) void main_gemm(const float* __restrict__ x,
                                                    const float* __restrict__ ipose,
                                                    const float* __restrict__ ishape,
                                                    const float* __restrict__ icam,
                                                    const unsigned short* __restrict__ Mb,
                                                    const float* __restrict__ Cb,
                                                    float* __restrict__ out) {
  __shared__ unsigned short Bl[160 * 424];       // 132.5 KB
  const int tid = threadIdx.x;

  {
    const bf16x8* src = (const bf16x8*)Mb;
    bf16x8* dst = (bf16x8*)Bl;
    for (int i = tid; i < 160 * 424 / 8; i += 512) dst[i] = src[i];
  }
  __syncthreads();

  const int w = tid >> 6, lane = tid & 63;
  const int m = lane & 15, g = lane >> 4;
  const int rowbase = blockIdx.x * 128 + w * 16;
  const int row = rowbase + m;
  const float* xr = x + (size_t)row * 256;
  const float* pr = ipose + (size_t)row * 144;

  float4 alo[13], ahi[13];
  #pragma unroll
  for (int k = 0; k < 8; k++) {
    const float* p = xr + k * 32 + g * 8;
    alo[k] = *(const float4*)p; ahi[k] = *(const float4*)(p + 4);
  }
  #pragma unroll
  for (int k = 8; k < 12; k++) {
    const float* p = pr + (k - 8) * 32 + g * 8;
    alo[k] = *(const float4*)p; ahi[k] = *(const float4*)(p + 4);
  }
  if (g < 2) {
    const float* p = pr + 128 + g * 8;
    alo[12] = *(const float4*)p; ahi[12] = *(const float4*)(p + 4);
  } else if (g == 2) {
    const float* p = ishape + (size_t)row * 10;
    alo[12] = make_float4(p[0], p[1], p[2], p[3]);
    ahi[12] = make_float4(p[4], p[5], p[6], p[7]);
  } else {
    const float* p = ishape + (size_t)row * 10;
    const float* q = icam + (size_t)row * 3;
    alo[12] = make_float4(p[8], p[9], q[0], q[1]);
    ahi[12] = make_float4(q[2], 0.f, 0.f, 0.f);
  }
  bf16x8 areg[13];
  #pragma unroll
  for (int k = 0; k < 13; k++) areg[k] = pack8(alo[k], ahi[k]);

  f32x4 acc[10];
  #pragma unroll
  for (int n = 0; n < 10; n++) acc[n] = (f32x4){0.f, 0.f, 0.f, 0.f};

  #pragma unroll
  for (int k = 0; k < 13; k++) {
    #pragma unroll
    for (int n = 0; n < 10; n++) {
      bf16x8 b = *(const bf16x8*)&Bl[(n * 16 + m) * 424 + k * 32 + g * 8];
      acc[n] = __builtin_amdgcn_mfma_f32_16x16x32_bf16(areg[k], b, acc[n], 0, 0, 0);
    }
  }

  // epilogue: C/D layout col=lane&15, row=(lane>>4)*4+reg  [m89-verified]
  #pragma unroll
  for (int n = 0; n < 10; n++) {
    int col = n * 16 + m;
    if (col < 157) {
      float bias = Cb[col];
      #pragma unroll
      for (int q = 0; q < 4; q++)
        out[(size_t)(rowbase + g * 4 + q) * 157 + col] = acc[n][q] + bias;
    }
  }
}

// ---------------------------------------------------------------------------
extern "C" void kernel_launch(void* const* d_in, const int* in_sizes, int n_in,
                              void* d_out, int out_size, void* d_ws, size_t ws_size,
                              hipStream_t stream) {
  const float* x      = (const float*)d_in[0];
  const float* ipose  = (const float*)d_in[1];
  const float* ishape = (const float*)d_in[2];
  const float* icam   = (const float*)d_in[3];
  const float* fc1w   = (const float*)d_in[4];
  const float* fc1b   = (const float*)d_in[5];
  const float* fc2w   = (const float*)d_in[6];
  const float* fc2b   = (const float*)d_in[7];
  const float* dsw    = (const float*)d_in[8];
  const float* dsb    = (const float*)d_in[9];
  const float* dcw    = (const float*)d_in[10];
  const float* dcb    = (const float*)d_in[11];
  const float* ktd    = (const float*)d_in[12];
  const float* ktdb   = (const float*)d_in[13];
  int rows = in_sizes[0] / 256;
  float* ws = (float*)d_ws;

  float* Gp = ws;                                      // 8*59200 = 473600 f
  float* Hp = ws + 473600;                             // 8*3520  = 28160 f -> 501760
  float* M0 = ws + 501760;                             // 160*424 = 67840 f -> 569600
  float* C0 = ws + 569600;                             // 160 f -> 569760
  float* S  = ws + 569760;                             // 144*144 = 20736 f -> 590496
  float* Cb = ws + 590496;                             // 160 f -> 590656
  unsigned short* Mb = (unsigned short*)(ws + 590656); // byte 2362624 (16-aligned)

  combine_mfma<<<dim3(47, 8), 640, 0, stream>>>(ktd, dcw, dsw, fc2w, fc2b,
                                                fc1w, fc1b, Gp, Hp, S);
  assembleM<<<160, 256, 0, stream>>>(Gp, Hp, dcw, dcb, dsb, ktd, ktdb, M0, C0);
  foldS<<<dim3(160, 2), 256, 0, stream>>>(S, M0, C0, Mb, Cb);
  main_gemm<<<rows / 128, 512, 0, stream>>>(x, ipose, ishape, icam, Mb, Cb,
                                            (float*)d_out);
}